// Round 9
// baseline (364.995 us; speedup 1.0000x reference)
//
#include <hip/hip_runtime.h>
#include <hip/hip_bf16.h>

#define N_NODES 50000
#define N_PAD   50048
#define N_EDGES 600000
#define IN_CH 128
#define HID 256
#define OUT_CH 128

typedef unsigned short u16;
typedef unsigned char u8;
typedef unsigned int u32;

typedef __attribute__((ext_vector_type(8))) short short8;
typedef __attribute__((ext_vector_type(4))) float f32x4;

typedef __attribute__((address_space(3))) u32 as3_u32;
typedef __attribute__((address_space(1))) const u32 as1_u32;

__device__ __forceinline__ float bf2f(u16 v) {
    unsigned u = ((unsigned)v) << 16;
    return __uint_as_float(u);
}
__device__ __forceinline__ u16 f2bf(float f) {
    unsigned u = __float_as_uint(f);
    u += 0x7FFF + ((u >> 16) & 1);   // round-to-nearest-even
    return (u16)(u >> 16);
}

// async global->LDS, 16B per lane; LDS dest = wave-uniform base + lane*16
__device__ __forceinline__ void async16(const void* g, void* l) {
    __builtin_amdgcn_global_load_lds((as1_u32*)g, (as3_u32*)l, 16, 0, 0);
}

// ---------------- fused prep: dtype detect (block-local) + conversions + histogram ----------------
#define NX (N_NODES * IN_CH)
#define CONV_TOTAL (NX + 256 * 256 + 256 * 128 + 256 * 512 + 128 * 256 + 896)
#define PREP_TOTAL (CONV_TOTAL + N_EDGES)

__global__ void prep_kernel(const void* __restrict__ x,
                            const void* __restrict__ W1l, const void* __restrict__ W1r,
                            const void* __restrict__ Ws,
                            const void* __restrict__ W2l, const void* __restrict__ W2r,
                            const void* __restrict__ Wo,
                            const void* __restrict__ b1, const void* __restrict__ bs,
                            const void* __restrict__ b2, const void* __restrict__ bo,
                            const int* __restrict__ ei, const void* __restrict__ em,
                            u16* __restrict__ xb, u16* __restrict__ Wc1,
                            u16* __restrict__ Wsb, u16* __restrict__ Wc2,
                            u16* __restrict__ Wob, float* __restrict__ biasf,
                            u32* __restrict__ degp, u32* __restrict__ rankp,
                            int* __restrict__ flags) {
    // --- block-local format detection (1.5 KB of L2-broadcast reads) ---
    __shared__ int s_inr, s_c1, s_c23, s_h1, s_h3, s_isbf, s_fmt;
    int t = threadIdx.x;
    if (t == 0) { s_inr = 0; s_c1 = 0; s_c23 = 0; s_h1 = 0; s_h3 = 0; }
    __syncthreads();
    if (t < 128) {                     // 256 u16 samples of x
        u32 w = ((const u32*)x)[t];
        int cnt = 0;
        int e0 = (w >> 7) & 0xFF;
        if (e0 >= 100 && e0 <= 133) cnt++;
        int e1 = (w >> 23) & 0xFF;
        if (e1 >= 100 && e1 <= 133) cnt++;
        if (cnt) atomicAdd(&s_inr, cnt);
    }
    {                                  // 1024 bytes of mask
        u32 w = ((const u32*)em)[t];
        u8 m1 = (u8)(w >> 8), m2 = (u8)(w >> 16), m3 = (u8)(w >> 24);
        if (m1) atomicAdd(&s_c1, 1);
        if (m1 == 0x3F) s_h1 = 1;      // benign race
        if (m2 || m3) atomicAdd(&s_c23, 1);
        if (m3 == 0x3F) s_h3 = 1;
    }
    __syncthreads();
    if (t == 0) {
        s_isbf = (s_inr >= 200) ? 1 : 0;
        int fmt;
        if (s_h1) fmt = 3;             // bf16
        else if (s_h3) fmt = 2;        // f32
        else if (s_c1 + s_c23 > 0) fmt = 0;  // u8 bool
        else fmt = 1;                  // int32
        s_fmt = fmt;
    }
    __syncthreads();
    int isbf = s_isbf, fmt = s_fmt;

    long gi = (long)blockIdx.x * 256 + t;
    if (gi == 0) { flags[0] = isbf; flags[1] = fmt; }
    auto cv = [&](const void* s, int idx) -> u16 {
        return isbf ? ((const u16*)s)[idx] : f2bf(((const float*)s)[idx]);
    };
    if (gi >= PREP_TOTAL) return;
    int i = (int)gi;
    if (i < NX) { xb[i] = cv(x, i); return; }
    i -= NX;
    if (i < 256 * 256) {               // Wc1 = [W1l | W1r] along k
        int n = i >> 8, k = i & 255;
        const void* s = (k < 128) ? W1l : W1r;
        Wc1[i] = cv(s, n * 128 + (k & 127));
        return;
    }
    i -= 256 * 256;
    if (i < 256 * 128) { Wsb[i] = cv(Ws, i); return; }
    i -= 256 * 128;
    if (i < 256 * 512) {               // Wc2 = [W2l | W2r] along k
        int n = i >> 9, k = i & 511;
        const void* s = (k < 256) ? W2l : W2r;
        Wc2[i] = cv(s, n * 256 + (k & 255));
        return;
    }
    i -= 256 * 512;
    if (i < 128 * 256) { Wob[i] = cv(Wo, i); return; }
    i -= 128 * 256;
    if (i < 896) {
        const void* s; int idx;
        if (i < 256)      { s = b1; idx = i; }
        else if (i < 512) { s = bs; idx = i - 256; }
        else if (i < 768) { s = b2; idx = i - 512; }
        else              { s = bo; idx = i - 768; }
        biasf[i] = isbf ? bf2f(((const u16*)s)[idx]) : ((const float*)s)[idx];
        return;
    }
    i -= 896;
    // --- packed dual histogram (deg lo16 | kept-deg hi16), one atomic/edge ---
    if (i < N_EDGES) {
        int d = ei[N_EDGES + i];
        bool keep;
        if (fmt == 0)      keep = ((const u8*)em)[i] != 0;
        else if (fmt == 1) keep = ((const int*)em)[i] != 0;
        else if (fmt == 2) keep = ((const float*)em)[i] != 0.f;
        else               keep = ((const u16*)em)[i] != 0;
        u32 inc = keep ? 0x10001u : 1u;
        u32 old = atomicAdd(&degp[d], inc);
        rankp[i] = (old & 0xffffu) | (keep ? (old & 0xffff0000u) : 0xffff0000u);
    }
}

// ---------------- fused per-chunk totals + last-block dual scan ----------------
__global__ void partial_scan_kernel(const u32* __restrict__ degp, u32* __restrict__ partial,
                                    int* __restrict__ pscan, u32* __restrict__ done, int nb) {
    __shared__ u32 sh[256];
    __shared__ int shi[256];
    __shared__ int lastf;
    int t = threadIdx.x;
    int i = blockIdx.x * 256 + t;
    sh[t] = (i < N_NODES) ? degp[i] : 0;
    __syncthreads();
    for (int s = 128; s > 0; s >>= 1) {
        if (t < s) sh[t] += sh[t + s];
        __syncthreads();
    }
    if (t == 0) {
        partial[blockIdx.x] = sh[0];
        __threadfence();
        u32 tk = atomicAdd(done, 1u);
        lastf = (tk == (u32)(gridDim.x - 1)) ? 1 : 0;
    }
    __syncthreads();
    if (!lastf) return;
    __threadfence();                   // acquire: other blocks' partial visible
    u32 pv = (t < nb) ? partial[t] : 0;
    int v1 = pv & 0xffff, v2 = pv >> 16;
    shi[t] = v1;
    __syncthreads();
    for (int o = 1; o < 256; o <<= 1) {
        int u = (t >= o) ? shi[t - o] : 0;
        __syncthreads();
        shi[t] += u;
        __syncthreads();
    }
    if (t < nb) pscan[t] = shi[t] - v1;
    __syncthreads();
    shi[t] = v2;
    __syncthreads();
    for (int o = 1; o < 256; o <<= 1) {
        int u = (t >= o) ? shi[t - o] : 0;
        __syncthreads();
        shi[t] += u;
        __syncthreads();
    }
    if (t < nb) pscan[nb + t] = shi[t] - v2;
}

// packed intra-chunk scan + global offsets -> both row_ptrs in one pass
__global__ void rowptr_kernel(const u32* __restrict__ degp, const int* __restrict__ pscan,
                              int* __restrict__ row_ptr, int* __restrict__ row_ptr2, int nb) {
    __shared__ u32 sh[256];
    int t = threadIdx.x;
    int i = blockIdx.x * 256 + t;
    u32 v = (i < N_NODES) ? degp[i] : 0;
    sh[t] = v;
    __syncthreads();
    for (int o = 1; o < 256; o <<= 1) {
        u32 u = (t >= o) ? sh[t - o] : 0;
        __syncthreads();
        sh[t] += u;
        __syncthreads();
    }
    u32 ex = sh[t] - v;                // packed exclusive scan
    if (i <= N_NODES) {
        row_ptr[i]  = pscan[blockIdx.x] + (int)(ex & 0xffff);
        row_ptr2[i] = pscan[nb + blockIdx.x] + (int)(ex >> 16);
    }
}

__global__ void scatter_csr_kernel(const int* __restrict__ ei, const u32* __restrict__ rankp,
                                   const int* __restrict__ row_ptr, const int* __restrict__ row_ptr2,
                                   int* __restrict__ srcs, int* __restrict__ srcs2) {
    int i = blockIdx.x * blockDim.x + threadIdx.x;
    if (i >= N_EDGES) return;
    int d = ei[N_EDGES + i];
    int s = ei[i];
    u32 rp = rankp[i];
    srcs[row_ptr[d] + (int)(rp & 0xffffu)] = s;
    u32 kr = rp >> 16;
    if (kr != 0xffffu) srcs2[row_ptr2[d] + (int)kr] = s;
}

// ---------------- CSR gathers: scalar-addressed via lane-preload + readlane ----------------
__global__ __launch_bounds__(256) void gather1_kernel(const int* __restrict__ row_ptr,
                                                      const int* __restrict__ srcs,
                                                      const u16* __restrict__ xb,
                                                      u16* __restrict__ aggb) {
    int wid = (blockIdx.x * blockDim.x + threadIdx.x) >> 6;
    int lane = threadIdx.x & 63;
    if (wid >= N_NODES) return;
    int start = row_ptr[wid], end = row_ptr[wid + 1];
    int dg = end - start;
    int sv = (lane < dg) ? srcs[start + lane] : 0;   // one coalesced preload
    float a0 = 0.f, a1 = 0.f, b0 = 0.f, b1 = 0.f;
    float c0 = 0.f, c1 = 0.f, d0 = 0.f, d1 = 0.f;
    int n = dg < 64 ? dg : 64;
    int e = 0;
    for (; e + 4 <= n; e += 4) {
        int s0 = __builtin_amdgcn_readlane(sv, e);
        int s1 = __builtin_amdgcn_readlane(sv, e + 1);
        int s2 = __builtin_amdgcn_readlane(sv, e + 2);
        int s3 = __builtin_amdgcn_readlane(sv, e + 3);
        u32 v0 = *(const u32*)(xb + (size_t)s0 * IN_CH + lane * 2);
        u32 v1 = *(const u32*)(xb + (size_t)s1 * IN_CH + lane * 2);
        u32 v2 = *(const u32*)(xb + (size_t)s2 * IN_CH + lane * 2);
        u32 v3 = *(const u32*)(xb + (size_t)s3 * IN_CH + lane * 2);
        a0 += bf2f((u16)v0); a1 += bf2f((u16)(v0 >> 16));
        b0 += bf2f((u16)v1); b1 += bf2f((u16)(v1 >> 16));
        c0 += bf2f((u16)v2); c1 += bf2f((u16)(v2 >> 16));
        d0 += bf2f((u16)v3); d1 += bf2f((u16)(v3 >> 16));
    }
    for (; e < n; e++) {
        int s0 = __builtin_amdgcn_readlane(sv, e);
        u32 v0 = *(const u32*)(xb + (size_t)s0 * IN_CH + lane * 2);
        a0 += bf2f((u16)v0); a1 += bf2f((u16)(v0 >> 16));
    }
    for (e = 64; e < dg; e++) {                      // rare tail (deg>64)
        int s0 = srcs[start + e];
        u32 v0 = *(const u32*)(xb + (size_t)s0 * IN_CH + lane * 2);
        a0 += bf2f((u16)v0); a1 += bf2f((u16)(v0 >> 16));
    }
    float inv = 1.f / fmaxf((float)dg, 1.f);
    float rx = (a0 + b0) + (c0 + d0);
    float ry = (a1 + b1) + (c1 + d1);
    u32 o = (u32)f2bf(rx * inv) | ((u32)f2bf(ry * inv) << 16);
    *(u32*)(aggb + (size_t)wid * IN_CH + lane * 2) = o;
}

__global__ __launch_bounds__(256) void gather2_kernel(const int* __restrict__ row_ptr2,
                                                      const int* __restrict__ srcs2,
                                                      const u16* __restrict__ h1b,
                                                      u16* __restrict__ aggb) {
    int wid = (blockIdx.x * blockDim.x + threadIdx.x) >> 6;
    int lane = threadIdx.x & 63;
    if (wid >= N_NODES) return;
    int start = row_ptr2[wid], end = row_ptr2[wid + 1];
    int dg = end - start;
    int sv = (lane < dg) ? srcs2[start + lane] : 0;
    float a0 = 0.f, a1 = 0.f, a2 = 0.f, a3 = 0.f;
    float b0 = 0.f, b1 = 0.f, b2 = 0.f, b3 = 0.f;
    float c0 = 0.f, c1 = 0.f, c2 = 0.f, c3 = 0.f;
    float d0 = 0.f, d1 = 0.f, d2 = 0.f, d3 = 0.f;
    int n = dg < 64 ? dg : 64;
    int e = 0;
    for (; e + 4 <= n; e += 4) {
        int s0 = __builtin_amdgcn_readlane(sv, e);
        int s1 = __builtin_amdgcn_readlane(sv, e + 1);
        int s2 = __builtin_amdgcn_readlane(sv, e + 2);
        int s3 = __builtin_amdgcn_readlane(sv, e + 3);
        uint2 v = *(const uint2*)(h1b + (size_t)s0 * HID + lane * 4);
        uint2 w = *(const uint2*)(h1b + (size_t)s1 * HID + lane * 4);
        uint2 y = *(const uint2*)(h1b + (size_t)s2 * HID + lane * 4);
        uint2 zz = *(const uint2*)(h1b + (size_t)s3 * HID + lane * 4);
        a0 += bf2f((u16)v.x); a1 += bf2f((u16)(v.x >> 16));
        a2 += bf2f((u16)v.y); a3 += bf2f((u16)(v.y >> 16));
        b0 += bf2f((u16)w.x); b1 += bf2f((u16)(w.x >> 16));
        b2 += bf2f((u16)w.y); b3 += bf2f((u16)(w.y >> 16));
        c0 += bf2f((u16)y.x); c1 += bf2f((u16)(y.x >> 16));
        c2 += bf2f((u16)y.y); c3 += bf2f((u16)(y.y >> 16));
        d0 += bf2f((u16)zz.x); d1 += bf2f((u16)(zz.x >> 16));
        d2 += bf2f((u16)zz.y); d3 += bf2f((u16)(zz.y >> 16));
    }
    for (; e < n; e++) {
        int s0 = __builtin_amdgcn_readlane(sv, e);
        uint2 v = *(const uint2*)(h1b + (size_t)s0 * HID + lane * 4);
        a0 += bf2f((u16)v.x); a1 += bf2f((u16)(v.x >> 16));
        a2 += bf2f((u16)v.y); a3 += bf2f((u16)(v.y >> 16));
    }
    for (e = 64; e < dg; e++) {                      // rare tail
        int s0 = srcs2[start + e];
        uint2 v = *(const uint2*)(h1b + (size_t)s0 * HID + lane * 4);
        a0 += bf2f((u16)v.x); a1 += bf2f((u16)(v.x >> 16));
        a2 += bf2f((u16)v.y); a3 += bf2f((u16)(v.y >> 16));
    }
    float inv = 1.f / fmaxf((float)dg, 1.f);
    float r0 = (a0 + b0) + (c0 + d0);
    float r1 = (a1 + b1) + (c1 + d1);
    float r2 = (a2 + b2) + (c2 + d2);
    float r3 = (a3 + b3) + (c3 + d3);
    u32 o0 = (u32)f2bf(r0 * inv) | ((u32)f2bf(r1 * inv) << 16);
    u32 o1 = (u32)f2bf(r2 * inv) | ((u32)f2bf(r3 * inv) << 16);
    u16* p = aggb + (size_t)wid * HID + lane * 4;
    *(u32*)p = o0;
    *(u32*)(p + 2) = o1;
}

// ---------------- unified LDS-staged MFMA GEMM ----------------
// BM=64 rows/block, full N in block, BK=64, double-buffered LDS staged via
// global_load_lds(16B). XOR-8 chunk swizzle: LDS slot s of row r holds global
// chunk s^(r&7) -> conflict-free ds_read_b128 fragment reads.
// MODE 1: sage1 (h1 = tanh(norm([agg|x]@Wc1^T + b1) + x@Wsb^T + bs))
// MODE 2: sage2 + FUSED final: h2 tile kept in LDS, out = h2@Wob^T + bo
template<int MODE>
__global__ __launch_bounds__(256, 2) void gemm_staged(
    const u16* __restrict__ A0, const u16* __restrict__ A1,
    const u16* __restrict__ W0, const u16* __restrict__ W1,
    const float* __restrict__ bias0, const float* __restrict__ bias1,
    u16* __restrict__ outb, void* __restrict__ outv, const int* __restrict__ flags) {

    constexpr int NT  = 4;                         // n-tiles per wave
    constexpr int Nw  = NT * 16;                   // cols per wave
    constexpr int NKS = (MODE == 1) ? 6 : 8;
    constexpr int BBYTES = NT * 64 * 128;          // 32 KB B-tile per buffer
    __shared__ __align__(16) u8 ldsmem[16384 + 2 * BBYTES];

    int tid = threadIdx.x;
    int w = tid >> 6, lane = tid & 63;
    int q = lane >> 4, c = lane & 15;
    int m_base = blockIdx.x * 64;
    int rj = lane >> 3, jj = lane & 7;
    int j16 = ((jj ^ rj) << 4);                    // swizzled global chunk offset

    f32x4 acc[4][NT], acc2[4][NT];
    const f32x4 z = {0.f, 0.f, 0.f, 0.f};
#pragma unroll
    for (int mt = 0; mt < 4; mt++)
#pragma unroll
        for (int nt = 0; nt < NT; nt++) { acc[mt][nt] = z; acc2[mt][nt] = z; }

    auto stage = [&](int ks, int b) {
        const u16* ap; int astr, kta;
        const u16* wp; int wstr, ktw;
        if (MODE == 1) {
            astr = 128;
            if (ks < 2)      { ap = A0; kta = ks; }
            else if (ks < 4) { ap = A1; kta = ks - 2; }
            else             { ap = A1; kta = ks - 4; }
            if (ks < 4) { wp = W0; wstr = 256; ktw = ks; }
            else        { wp = W1; wstr = 128; ktw = ks - 4; }
        } else {
            astr = 256;
            if (ks < 4) { ap = A0; kta = ks; } else { ap = A1; kta = ks - 4; }
            wp = W0; wstr = 512; ktw = ks;
        }
#pragma unroll
        for (int t = 0; t < 2; t++) {               // A: 16 rows/wave
            int r = w * 16 + t * 8;
            const u8* g = (const u8*)(ap + (size_t)(m_base + r + rj) * astr) + kta * 128 + j16;
            async16(g, ldsmem + b * 8192 + r * 128);
        }
#pragma unroll
        for (int t = 0; t < NT * 2; t++) {          // B: Nw rows/wave
            int n = w * Nw + t * 8;
            const u8* g = (const u8*)(wp + (size_t)(n + rj) * wstr) + ktw * 128 + j16;
            async16(g, ldsmem + 16384 + b * BBYTES + n * 128);
        }
    };

    auto compute = [&](int b, f32x4 (*tgt)[NT]) {
        const u8* ab = ldsmem + b * 8192;
        const u8* bb = ldsmem + 16384 + b * BBYTES;
#pragma unroll
        for (int kk = 0; kk < 2; kk++) {
            int sA = (((kk * 4 + q) ^ (c & 7)) << 4);
            short8 af[4], bfr[NT];
#pragma unroll
            for (int mt = 0; mt < 4; mt++)
                af[mt] = *(const short8*)(ab + (mt * 16 + c) * 128 + sA);
#pragma unroll
            for (int nt = 0; nt < NT; nt++)
                bfr[nt] = *(const short8*)(bb + (w * Nw + nt * 16 + c) * 128 + sA);
#pragma unroll
            for (int mt = 0; mt < 4; mt++)
#pragma unroll
                for (int nt = 0; nt < NT; nt++)
                    tgt[mt][nt] = __builtin_amdgcn_mfma_f32_16x16x32_bf16(af[mt], bfr[nt], tgt[mt][nt], 0, 0, 0);
        }
    };

    stage(0, 0);
    int b = 0;
#pragma unroll
    for (int ks = 0; ks < NKS; ks++) {
        __syncthreads();                  // drains staging of buffer b
        if (ks + 1 < NKS) stage(ks + 1, b ^ 1);
        if (MODE == 1 && ks >= 4) compute(b, acc2);
        else                      compute(b, acc);
        b ^= 1;
    }
    __syncthreads();

    // ---------------- epilogue: bias + row L2-norm ----------------
    float* redf = (float*)ldsmem;     // A-staging region reuse: red[64][4] + invn[64]
    float bcol[NT], b2col[NT];
#pragma unroll
    for (int nt = 0; nt < NT; nt++) {
        int col = w * Nw + nt * 16 + c;
        bcol[nt] = bias0[col];
        if (MODE == 1) b2col[nt] = bias1[col];
    }
    float s[4][4];
#pragma unroll
    for (int mt = 0; mt < 4; mt++)
#pragma unroll
        for (int r = 0; r < 4; r++) {
            float t = 0.f;
#pragma unroll
            for (int nt = 0; nt < NT; nt++) {
                float v = acc[mt][nt][r] + bcol[nt];
                acc[mt][nt][r] = v;
                t += v * v;
            }
            s[mt][r] = t;
        }
#pragma unroll
    for (int off = 1; off < 16; off <<= 1) {
#pragma unroll
        for (int mt = 0; mt < 4; mt++)
#pragma unroll
            for (int r = 0; r < 4; r++)
                s[mt][r] += __shfl_xor(s[mt][r], off, 64);
    }
    if (c == 0) {
#pragma unroll
        for (int mt = 0; mt < 4; mt++)
#pragma unroll
            for (int r = 0; r < 4; r++)
                redf[(mt * 16 + q * 4 + r) * 4 + w] = s[mt][r];
    }
    __syncthreads();
    if (tid < 64) {
        float t = redf[tid * 4] + redf[tid * 4 + 1] + redf[tid * 4 + 2] + redf[tid * 4 + 3];
        redf[256 + tid] = 1.f / fmaxf(sqrtf(t), 1e-12f);
    }
    __syncthreads();

    if constexpr (MODE == 1) {
#pragma unroll
        for (int mt = 0; mt < 4; mt++)
#pragma unroll
            for (int r = 0; r < 4; r++) {
                int rl = mt * 16 + q * 4 + r;
                int row = m_base + rl;
                if (row < N_NODES) {
                    float iv = redf[256 + rl];
#pragma unroll
                    for (int nt = 0; nt < NT; nt++) {
                        int col = w * Nw + nt * 16 + c;
                        float h = acc[mt][nt][r] * iv + acc2[mt][nt][r] + b2col[nt];
                        outb[(size_t)row * HID + col] = f2bf(tanhf(h));
                    }
                }
            }
    } else {
        // ---- write h2 tile (64x256 bf16) into LDS (B buffer 0), swizzled layout ----
        u8* h2l = ldsmem + 16384;
#pragma unroll
        for (int mt = 0; mt < 4; mt++)
#pragma unroll
            for (int r = 0; r < 4; r++) {
                int rl = mt * 16 + q * 4 + r;
                float iv = redf[256 + rl];
#pragma unroll
                for (int nt = 0; nt < NT; nt++) {
                    int col = w * Nw + nt * 16 + c;
                    u16 val = f2bf(tanhf(acc[mt][nt][r] * iv));
                    int ksn = col >> 6, cc = col & 63;
                    int slot = (cc >> 3) ^ (rl & 7);
                    *(u16*)(h2l + rl * 512 + ksn * 128 + slot * 16 + (cc & 7) * 2) = val;
                }
            }
        // ---- fused final projection: out = h2 @ Wob^T + bo (K=256, N=128) ----
        f32x4 accf[4][2];
#pragma unroll
        for (int mt = 0; mt < 4; mt++)
#pragma unroll
            for (int nt = 0; nt < 2; nt++) accf[mt][nt] = z;

        auto stageW = [&](int ksf, int fb) {
#pragma unroll
            for (int tt = 0; tt < 4; tt++) {        // 32 rows/wave of Wob
                int n = w * 32 + tt * 8;
                const u8* g = (const u8*)W1 + (size_t)(n + rj) * 512 + ksf * 128 + j16;
                async16(g, ldsmem + 16384 + BBYTES + fb * 16384 + n * 128);
            }
        };
        stageW(0, 0);
        int fb = 0;
#pragma unroll
        for (int ksf = 0; ksf < 4; ksf++) {
            __syncthreads();              // drains stageW(fb) + (first iter) h2 ds_writes
            if (ksf < 3) stageW(ksf + 1, fb ^ 1);
            const u8* bb2 = ldsmem + 16384 + BBYTES + fb * 16384;
#pragma unroll
            for (int kk = 0; kk < 2; kk++) {
                int sA = (((kk * 4 + q) ^ (c & 7)) << 4);
                short8 af[4], bf2[2];
#pragma unroll
                for (int mt = 0; mt < 4; mt++)
                    af[mt] = *(const short8*)(h2l + (mt * 16 + c) * 512 + ksf * 128 + sA);
#pragma unroll
                for (int nt = 0; nt < 2; nt++)
                    bf2[nt] = *(const short8*)(bb2 + (w * 32 + nt * 16 + c) * 128 + sA);
#pragma unroll
                for (int mt = 0; mt < 4; mt++)
#pragma unroll
                    for (int nt = 0; nt < 2; nt++)
                        accf[mt][nt] = __builtin_amdgcn_mfma_f32_16x16x32_bf16(af[mt], bf2[nt], accf[mt][nt], 0, 0, 0);
            }
            fb ^= 1;
        }
        float bfo[2];
#pragma unroll
        for (int nt = 0; nt < 2; nt++) bfo[nt] = bias1[w * 32 + nt * 16 + c];
        int isbf = flags[0];
#pragma unroll
        for (int mt = 0; mt < 4; mt++)
#pragma unroll
            for (int r = 0; r < 4; r++) {
                int row = m_base + mt * 16 + q * 4 + r;
                if (row < N_NODES) {
#pragma unroll
                    for (int nt = 0; nt < 2; nt++) {
                        float v = accf[mt][nt][r] + bfo[nt];
                        int col = w * 32 + nt * 16 + c;
                        if (isbf) ((u16*)outv)[(size_t)row * OUT_CH + col] = f2bf(v);
                        else      ((float*)outv)[(size_t)row * OUT_CH + col] = v;
                    }
                }
            }
    }
}

extern "C" void kernel_launch(void* const* d_in, const int* in_sizes, int n_in,
                              void* d_out, int out_size, void* d_ws, size_t ws_size,
                              hipStream_t stream) {
    const void* x    = d_in[0];
    const int*  ei   = (const int*)d_in[1];
    const void* em   = d_in[2];
    const void* W1l  = d_in[3];
    const void* b1   = d_in[4];
    const void* W1r  = d_in[5];
    const void* Ws   = d_in[6];
    const void* bs   = d_in[7];
    const void* W2l  = d_in[8];
    const void* b2   = d_in[9];
    const void* W2r  = d_in[10];
    const void* Wo   = d_in[11];
    const void* bo   = d_in[12];

    char* p = (char*)d_ws;
    auto carve = [&](size_t bytes) { char* r = p; p += (bytes + 63) & ~(size_t)63; return r; };
    int*   flags   = (int*)carve(256);
    u16*   xb      = (u16*)carve((size_t)N_PAD * IN_CH * 2);
    u16*   h1b     = (u16*)carve((size_t)N_PAD * HID * 2);
    u16*   aggb    = (u16*)carve((size_t)N_PAD * HID * 2);   // layer1 view: [N_PAD][128]
    u16*   Wc1     = (u16*)carve(256 * 256 * 2);
    u16*   Wsb     = (u16*)carve(256 * 128 * 2);
    u16*   Wc2     = (u16*)carve(256 * 512 * 2);
    u16*   Wob     = (u16*)carve(128 * 256 * 2);
    float* biasf   = (float*)carve(896 * 4);   // [b1|bs|b2|bo]
    u32*   degp    = (u32*)carve(50240 * 4);   // + done counter at [50176]
    int*   row_ptr = (int*)carve(50056 * 4);
    int*   row_ptr2= (int*)carve(50056 * 4);
    u32*   partial = (u32*)carve(256 * 4);
    int*   pscan   = (int*)carve(512 * 4);
    u32*   rankp   = (u32*)carve((size_t)N_EDGES * 4);
    int*   srcs    = (int*)carve((size_t)N_EDGES * 4);
    int*   srcs2   = (int*)carve((size_t)N_EDGES * 4);
    float* b1f = biasf, *bsf = biasf + 256, *b2f = biasf + 512, *bof = biasf + 768;
    u32*   done = degp + 50176;
    (void)ws_size; (void)in_sizes; (void)n_in; (void)out_size;

    // zero degp + done counter (one fill)
    hipMemsetAsync(degp, 0, 50240 * sizeof(u32), stream);

    // fused: detect (block-local) + all conversions + packed dual histogram
    prep_kernel<<<(PREP_TOTAL + 255) / 256, 256, 0, stream>>>(
        x, W1l, W1r, Ws, W2l, W2r, Wo, b1, bs, b2, bo, ei, em,
        xb, Wc1, Wsb, Wc2, Wob, biasf, degp, rankp, flags);

    const int NB = (N_NODES + 255) / 256;   // 196
    partial_scan_kernel<<<NB, 256, 0, stream>>>(degp, partial, pscan, done, NB);
    rowptr_kernel<<<NB, 256, 0, stream>>>(degp, pscan, row_ptr, row_ptr2, NB);
    scatter_csr_kernel<<<(N_EDGES + 255) / 256, 256, 0, stream>>>(ei, rankp, row_ptr, row_ptr2, srcs, srcs2);

    const int GB = N_PAD / 64;   // 782 blocks

    // ---- layer 1 ----
    gather1_kernel<<<(N_NODES * 64) / 256, 256, 0, stream>>>(row_ptr, srcs, xb, aggb);
    gemm_staged<1><<<GB, 256, 0, stream>>>(aggb, xb, Wc1, Wsb, b1f, bsf, h1b, nullptr, flags);

    // ---- layer 2 + fused final ----
    gather2_kernel<<<(N_NODES * 64) / 256, 256, 0, stream>>>(row_ptr2, srcs2, h1b, aggb);
    gemm_staged<2><<<GB, 256, 0, stream>>>(aggb, h1b, Wc2, Wob, b2f, bof, nullptr, d_out, flags);
}